// Round 5
// baseline (7992.198 us; speedup 1.0000x reference)
//
#include <hip/hip_runtime.h>

#define BATCHES 16
#define NG 2048
#define FDIM 1024
#define EPG 65536
#define NTOT (BATCHES*NG)      // 32768
#define ETOT (BATCHES*EPG)     // 1048576
#define STEPS 64
#define NBLK 512
#define NTHR 256
#define BLK_PER_BATCH (NBLK/BATCHES)          // 32
#define ROWS_PER_BLK (NG/BLK_PER_BATCH)       // 64
#define EDGE_PER_BLK (ETOT/NBLK)              // 2048

// ws layout (double-sized slots):
// [0)        xb0[NTOT]
// [NTOT)     xb1[NTOT]
// [2N)       pred[NTOT]
// [3N)       coef[2][BATCHES*FDIM]
// ...        quad[2][16], lin[2][16], minr(u64)[2][16], barrier(u64)[2]
#define WS_XB0   0
#define WS_XB1   (NTOT)
#define WS_PRED  (2*NTOT)
#define WS_COEF  (3*NTOT)
#define WS_QUAD  (3*NTOT + 2*BATCHES*FDIM)
#define WS_LIN   (WS_QUAD + 2*BATCHES)
#define WS_MINR  (WS_LIN + 2*BATCHES)          // u64 cells
#define WS_BAR   (WS_MINR + 2*BATCHES)         // u64 cells: [arrive, gen]

__device__ __forceinline__ double ld_ag(const double* p) {
    return __hip_atomic_load(p, __ATOMIC_RELAXED, __HIP_MEMORY_SCOPE_AGENT);
}
__device__ __forceinline__ void st_ag(double* p, double v) {
    __hip_atomic_store(p, v, __ATOMIC_RELAXED, __HIP_MEMORY_SCOPE_AGENT);
}
__device__ __forceinline__ unsigned long long ldu64_ag(const unsigned long long* p) {
    return __hip_atomic_load(p, __ATOMIC_RELAXED, __HIP_MEMORY_SCOPE_AGENT);
}
__device__ __forceinline__ void stu64_ag(unsigned long long* p, unsigned long long v) {
    __hip_atomic_store(p, v, __ATOMIC_RELAXED, __HIP_MEMORY_SCOPE_AGENT);
}

// Lean grid barrier: no L2 writeback/invalidate. All cross-block data uses
// the coherent (LLC) path, so only completion ordering is needed.
__device__ __forceinline__ void grid_barrier(unsigned long long* bar,
                                             unsigned long long g, int tid) {
    asm volatile("s_waitcnt vmcnt(0)" ::: "memory");  // all my LLC-path ops performed
    __syncthreads();
    if (tid == 0) {
        unsigned long long old = __hip_atomic_fetch_add(
            &bar[0], 1ULL, __ATOMIC_RELAXED, __HIP_MEMORY_SCOPE_AGENT);
        if (old == (unsigned long long)NBLK * g - 1ULL) {
            stu64_ag(&bar[1], g);
        } else {
            while (ldu64_ag(&bar[1]) < g) __builtin_amdgcn_s_sleep(2);
        }
    }
    __syncthreads();
}

__device__ __forceinline__ double block_reduce_sum(double v, double* s_red) {
    for (int off = 32; off > 0; off >>= 1)
        v += __shfl_down(v, off, 64);
    __syncthreads();
    int lane = threadIdx.x & 63;
    int wave = threadIdx.x >> 6;
    if (lane == 0) s_red[wave] = v;
    __syncthreads();
    return (s_red[0] + s_red[1]) + (s_red[2] + s_red[3]);
}

__global__ __launch_bounds__(NTHR, 2)
void GradSolver_58102317580919_kernel(
    const float* __restrict__ x_start,
    const float* __restrict__ rhs,
    const float* __restrict__ proj,
    const float* __restrict__ q,
    const float* __restrict__ obj_solution,
    const int*   __restrict__ edge_index,
    const float* __restrict__ edge_weight,
    float* __restrict__ out,                // [NTOT bestx][B best][B*STEPS gaps]
    void* __restrict__ wsv)
{
    double* ws = (double*)wsv;
    double* xb[2] = { ws + WS_XB0, ws + WS_XB1 };
    double* pred  = ws + WS_PRED;
    double* coef  = ws + WS_COEF;                    // [2][B*F]
    double* quad  = ws + WS_QUAD;                    // [2][16]
    double* lin   = ws + WS_LIN;                     // [2][16]
    unsigned long long* minr = (unsigned long long*)(ws + WS_MINR); // [2][16]
    unsigned long long* bar  = (unsigned long long*)(ws + WS_BAR);

    const int tid   = threadIdx.x;
    const int bid   = blockIdx.x;
    const int batch = bid / BLK_PER_BATCH;
    const int row_base = batch * NG + (bid % BLK_PER_BATCH) * ROWS_PER_BLK;

    const unsigned long long DINF = 0x7FF0000000000000ULL;

    __shared__ double s_d[ROWS_PER_BLK];
    __shared__ double s_x[ROWS_PER_BLK];
    __shared__ double s_pred[ROWS_PER_BLK];
    __shared__ double s_coef[FDIM];
    __shared__ double s_red[4];
    __shared__ double s_bestobj;

    unsigned long long g = 0;
    double tau = 1.0;

    // ---- P0: zero accumulators (LLC path; barrier region pre-zeroed by memset) ----
    if (tid < 64) st_ag(&coef[bid*64 + tid], 0.0);   // 2*16384 / 512 = 64 each
    if (bid == 0 && tid < 16) {
        st_ag(&quad[tid], 0.0);      st_ag(&quad[16+tid], 0.0);
        st_ag(&lin[tid],  0.0);      st_ag(&lin[16+tid],  0.0);
        stu64_ag(&minr[tid], DINF);  stu64_ag(&minr[16+tid], DINF);
    }
    if (tid == 0) s_bestobj = __longlong_as_double((long long)DINF);
    grid_barrier(bar, ++g, tid);

    for (int k = 0; k <= STEPS; ++k) {
        const int p  = k & 1;        // this step's accumulation parity
        const int pp = 1 - p;        // previous step's parity
        // ================= Phase CA =================
        double alpha = 0.0;
        if (k > 0) {
            unsigned long long m = ldu64_ag(&minr[pp*16 + batch]);
            alpha = fmin(__longlong_as_double((long long)m), 1.0) * 0.995;
        }
        double xv = 0.0;
        if (tid < ROWS_PER_BLK) {
            xv = (k == 0) ? (double)x_start[row_base + tid]
                          : s_x[tid] + alpha * s_pred[tid];
            s_x[tid] = xv;
            st_ag(&xb[p][row_base + tid], xv);
            if (k < STEPS)
                s_d[tid] = -xv + (double)rhs[row_base + tid] + 0.1 * tau / (xv + tau);
        }
        tau = fmax(tau * 0.5, 1e-5);
        // resets (all barrier-separated from their readers/writers):
        if (k >= 1 && tid < 32) st_ag(&coef[pp*(BATCHES*FDIM) + bid*32 + tid], 0.0);
        if (k < STEPS && bid == 0 && tid < 16) stu64_ag(&minr[p*16 + tid], DINF);

        // lin += q . x_k
        double lp = (tid < ROWS_PER_BLK) ? (double)q[row_base + tid] * xv : 0.0;
        double ls = block_reduce_sum(lp, s_red);
        if (tid == 0) unsafeAtomicAdd(&lin[p*16 + batch], ls);

        // quad += w * x_k[s] * x_k[d]  (x_k reconstructed from stale x/pred)
        {
            const int e0 = bid * EDGE_PER_BLK;
            double qp = 0.0;
            if (k == 0) {
                #pragma unroll 4
                for (int j = 0; j < EDGE_PER_BLK/NTHR; ++j) {
                    int e  = e0 + tid + j*NTHR;
                    int si = edge_index[e];
                    int di = edge_index[ETOT + e];
                    qp += (double)edge_weight[e] * (double)x_start[si] * (double)x_start[di];
                }
            } else {
                const double* xprev = xb[pp];
                #pragma unroll 4
                for (int j = 0; j < EDGE_PER_BLK/NTHR; ++j) {
                    int e  = e0 + tid + j*NTHR;
                    int si = edge_index[e];
                    int di = edge_index[ETOT + e];
                    double xs = ld_ag(&xprev[si]) + alpha * ld_ag(&pred[si]);
                    double xd = ld_ag(&xprev[di]) + alpha * ld_ag(&pred[di]);
                    qp += (double)edge_weight[e] * xs * xd;
                }
            }
            double qs = block_reduce_sum(qp, s_red);
            if (tid == 0) unsafeAtomicAdd(&quad[p*16 + batch], qs);
        }

        // coef += P^T d   (block-own rows only — no sync needed beyond LDS)
        if (k < STEPS) {
            __syncthreads();   // s_d complete
            double a0 = 0.0, a1 = 0.0, a2 = 0.0, a3 = 0.0;
            const float4* P4 = (const float4*)(proj + (size_t)row_base * FDIM);
            #pragma unroll 8
            for (int r = 0; r < ROWS_PER_BLK; ++r) {
                float4 pv = P4[r*(FDIM/4) + tid];
                double dv = s_d[r];
                a0 += (double)pv.x*dv; a1 += (double)pv.y*dv;
                a2 += (double)pv.z*dv; a3 += (double)pv.w*dv;
            }
            double* cf = coef + p*(BATCHES*FDIM) + batch*FDIM + 4*tid;
            unsafeAtomicAdd(cf+0, a0); unsafeAtomicAdd(cf+1, a1);
            unsafeAtomicAdd(cf+2, a2); unsafeAtomicAdd(cf+3, a3);
        }
        grid_barrier(bar, ++g, tid);

        // ================= Phase B =================
        double cur = 0.5 * ld_ag(&quad[p*16 + batch]) + ld_ag(&lin[p*16 + batch]);
        double bo  = s_bestobj;
        bool better = cur < bo;
        double nb  = better ? cur : bo;
        __syncthreads();
        if (tid == 0) s_bestobj = nb;

        if ((bid % BLK_PER_BATCH) == 0 && tid == 0) {
            double opt = (double)obj_solution[batch];
            double gap = fabs((opt - nb)/opt);
            if (k >= 1)     out[NTOT + BATCHES + batch*STEPS + (k-1)] = (float)gap;
            if (k == STEPS) out[NTOT + batch] = (float)gap;
        }
        if (better && tid < ROWS_PER_BLK)
            out[row_base + tid] = (float)s_x[tid];

        if (k == STEPS) break;

        if (bid == 0 && tid < 16) {     // zero next step's obj accumulators
            st_ag(&quad[pp*16 + tid], 0.0);
            st_ag(&lin[pp*16 + tid],  0.0);
        }

        // stage coef -> LDS
        #pragma unroll
        for (int j = 0; j < 4; ++j)
            s_coef[tid + 256*j] = ld_ag(&coef[p*(BATCHES*FDIM) + batch*FDIM + tid + 256*j]);
        __syncthreads();

        // pred = P coef  (own rows), ratio min
        {
            const int wave = tid >> 6, lane = tid & 63;
            double c[16];
            #pragma unroll
            for (int j = 0; j < 4; ++j) {
                int f = 4*(lane + 64*j);
                c[4*j+0] = s_coef[f+0]; c[4*j+1] = s_coef[f+1];
                c[4*j+2] = s_coef[f+2]; c[4*j+3] = s_coef[f+3];
            }
            double wmin = 1e300;
            for (int i = 0; i < ROWS_PER_BLK/4; ++i) {
                int r  = wave * (ROWS_PER_BLK/4) + i;
                int gr = row_base + r;
                const float4* Pr = (const float4*)(proj + (size_t)gr * FDIM);
                double dot = 0.0;
                #pragma unroll
                for (int j = 0; j < 4; ++j) {
                    float4 pv = Pr[lane + 64*j];
                    dot += (double)pv.x*c[4*j+0] + (double)pv.y*c[4*j+1]
                         + (double)pv.z*c[4*j+2] + (double)pv.w*c[4*j+3];
                }
                for (int off = 32; off > 0; off >>= 1)
                    dot += __shfl_down(dot, off, 64);
                if (lane == 0) {
                    s_pred[r] = dot;
                    st_ag(&pred[gr], dot);
                    if (dot < 0.0) wmin = fmin(wmin, s_x[r] / (-dot));
                }
            }
            if (lane == 0)
                atomicMin(&minr[p*16 + batch], (unsigned long long)__double_as_longlong(wmin));
        }
        grid_barrier(bar, ++g, tid);
    }
}

extern "C" void kernel_launch(void* const* d_in, const int* in_sizes, int n_in,
                              void* d_out, int out_size, void* d_ws, size_t ws_size,
                              hipStream_t stream) {
    const float* x_start      = (const float*)d_in[0];
    const float* rhs          = (const float*)d_in[1];
    const float* proj         = (const float*)d_in[2];
    const float* q            = (const float*)d_in[3];
    const float* obj_solution = (const float*)d_in[4];
    const int*   edge_index   = (const int*)d_in[5];
    const float* edge_weight  = (const float*)d_in[6];
    float* out = (float*)d_out;
    void* ws   = d_ws;

    // zero the barrier cells (arrive, gen) — ws is poisoned 0xAA each launch
    hipMemsetAsync((char*)d_ws + (size_t)WS_BAR * 8, 0, 16, stream);

    void* args[] = { (void*)&x_start, (void*)&rhs, (void*)&proj, (void*)&q,
                     (void*)&obj_solution, (void*)&edge_index, (void*)&edge_weight,
                     (void*)&out, (void*)&ws };
    hipLaunchCooperativeKernel((void*)GradSolver_58102317580919_kernel,
                               dim3(NBLK), dim3(NTHR), args, 0, stream);
}

// Round 7
// 7557.500 us; speedup vs baseline: 1.0575x; 1.0575x over previous
//
#include <hip/hip_runtime.h>

#define BATCHES 16
#define NG 2048
#define FDIM 1024
#define EPG 65536
#define NTOT (BATCHES*NG)      // 32768
#define ETOT (BATCHES*EPG)     // 1048576
#define STEPS 64
#define NBLK 512
#define NTHR 256
#define BLK_PER_BATCH (NBLK/BATCHES)          // 32
#define ROWS_PER_BLK (NG/BLK_PER_BATCH)       // 64
#define EDGE_PER_BLK (ETOT/NBLK)              // 2048

// ws layout — byte-identical to the verified round-0/5 kernel:
#define WS_XB0   0
#define WS_XB1   (NTOT)
#define WS_PRED  (2*NTOT)
#define WS_COEF  (3*NTOT)
#define WS_QUAD  (3*NTOT + 2*BATCHES*FDIM)
#define WS_LIN   (WS_QUAD + 2*BATCHES)
#define WS_MINR  (WS_LIN + 2*BATCHES)          // u64 cells
#define WS_BAR   (WS_MINR + 2*BATCHES)         // u64 cells: [arrive, gen]

__device__ __forceinline__ double ld_ag(const double* p) {
    return __hip_atomic_load(p, __ATOMIC_RELAXED, __HIP_MEMORY_SCOPE_AGENT);
}
__device__ __forceinline__ void st_ag(double* p, double v) {
    __hip_atomic_store(p, v, __ATOMIC_RELAXED, __HIP_MEMORY_SCOPE_AGENT);
}
__device__ __forceinline__ unsigned long long ldu64_ag(const unsigned long long* p) {
    return __hip_atomic_load(p, __ATOMIC_RELAXED, __HIP_MEMORY_SCOPE_AGENT);
}
__device__ __forceinline__ void stu64_ag(unsigned long long* p, unsigned long long v) {
    __hip_atomic_store(p, v, __ATOMIC_RELAXED, __HIP_MEMORY_SCOPE_AGENT);
}

// Lean grid barrier (hand-rolled atomics; does NOT require cooperative
// launch API — only actual co-residency, guaranteed by capacity:
// 512 blocks x ~27KB LDS = 2 blocks/CU = 53KB <= 160KB physical).
__device__ __forceinline__ void grid_barrier(unsigned long long* bar,
                                             unsigned long long g, int tid) {
    asm volatile("s_waitcnt vmcnt(0)" ::: "memory");  // all my LLC-path ops performed
    __syncthreads();
    if (tid == 0) {
        unsigned long long old = __hip_atomic_fetch_add(
            &bar[0], 1ULL, __ATOMIC_RELAXED, __HIP_MEMORY_SCOPE_AGENT);
        if (old == (unsigned long long)NBLK * g - 1ULL) {
            stu64_ag(&bar[1], g);
        } else {
            while (ldu64_ag(&bar[1]) < g) __builtin_amdgcn_s_sleep(2);
        }
    }
    __syncthreads();
}

__device__ __forceinline__ double block_reduce_sum(double v, double* s_red) {
    for (int off = 32; off > 0; off >>= 1)
        v += __shfl_down(v, off, 64);
    __syncthreads();
    int lane = threadIdx.x & 63;
    int wave = threadIdx.x >> 6;
    if (lane == 0) s_red[wave] = v;
    __syncthreads();
    return (s_red[0] + s_red[1]) + (s_red[2] + s_red[3]);
}

__global__ __launch_bounds__(NTHR, 2)
void GradSolver_58102317580919_kernel(
    const float* __restrict__ x_start,
    const float* __restrict__ rhs,
    const float* __restrict__ proj,
    const float* __restrict__ q,
    const float* __restrict__ obj_solution,
    const int*   __restrict__ edge_index,
    const float* __restrict__ edge_weight,
    float* __restrict__ out,                // [NTOT bestx][B best][B*STEPS gaps]
    void* __restrict__ wsv)
{
    double* ws = (double*)wsv;
    double* xb[2] = { ws + WS_XB0, ws + WS_XB1 };
    double* pred  = ws + WS_PRED;
    double* coef  = ws + WS_COEF;                    // [2][B*F]
    double* quad  = ws + WS_QUAD;                    // [2][16]
    double* lin   = ws + WS_LIN;                     // [2][16]
    unsigned long long* minr = (unsigned long long*)(ws + WS_MINR); // [2][16]
    unsigned long long* bar  = (unsigned long long*)(ws + WS_BAR);

    const int tid   = threadIdx.x;
    const int bid   = blockIdx.x;
    const int batch = bid / BLK_PER_BATCH;
    const int row_base = batch * NG + (bid % BLK_PER_BATCH) * ROWS_PER_BLK;
    const int nbase = batch * NG;

    const unsigned long long DINF = 0x7FF0000000000000ULL;

    // LDS ~26.6 KB/block; 2 blocks/CU = 53 KB <= 160 KB physical.
    __shared__ double s_d[ROWS_PER_BLK];
    __shared__ double s_x[ROWS_PER_BLK];
    __shared__ double s_pred[ROWS_PER_BLK];
    __shared__ double s_coef[FDIM];
    __shared__ double s_xp[NG];                  // batch-wide x_k (alpha folded in)
    __shared__ double s_red[4];
    __shared__ double s_bestobj;

    unsigned long long g = 0;
    double tau = 1.0;

    // ---- P0: zero accumulators (LLC path; barrier region pre-zeroed by memset) ----
    if (tid < 64) st_ag(&coef[bid*64 + tid], 0.0);   // 2*16384 / 512 = 64 each
    if (bid == 0 && tid < 16) {
        st_ag(&quad[tid], 0.0);      st_ag(&quad[16+tid], 0.0);
        st_ag(&lin[tid],  0.0);      st_ag(&lin[16+tid],  0.0);
        stu64_ag(&minr[tid], DINF);  stu64_ag(&minr[16+tid], DINF);
    }
    if (tid == 0) s_bestobj = __longlong_as_double((long long)DINF);
    grid_barrier(bar, ++g, tid);

    for (int k = 0; k <= STEPS; ++k) {
        const int p  = k & 1;        // this step's accumulation parity
        const int pp = 1 - p;        // previous step's parity
        // ================= Phase CA =================
        double alpha = 0.0;
        if (k > 0) {
            unsigned long long m = ldu64_ag(&minr[pp*16 + batch]);
            alpha = fmin(__longlong_as_double((long long)m), 1.0) * 0.995;
        }
        double xv = 0.0;
        if (tid < ROWS_PER_BLK) {
            xv = (k == 0) ? (double)x_start[row_base + tid]
                          : s_x[tid] + alpha * s_pred[tid];
            s_x[tid] = xv;
            st_ag(&xb[p][row_base + tid], xv);
            if (k < STEPS)
                s_d[tid] = -xv + (double)rhs[row_base + tid] + 0.1 * tau / (xv + tau);
        }
        tau = fmax(tau * 0.5, 1e-5);

        // stage batch-wide x_k -> LDS, coalesced.  Same per-endpoint
        // expression the verified kernel evaluated inside the edge gather
        // (xprev[i] + alpha*pred[i]) — identical sources, same barrier
        // interval, batch-uniform alpha => bit-identical values.
        if (k == 0) {
            #pragma unroll
            for (int j = 0; j < NG/NTHR; ++j) {
                int i = tid + j*NTHR;
                s_xp[i] = (double)x_start[nbase + i];
            }
        } else {
            const double* xprev = xb[pp];
            #pragma unroll
            for (int j = 0; j < NG/NTHR; ++j) {
                int i = tid + j*NTHR;
                s_xp[i] = ld_ag(&xprev[nbase + i]) + alpha * ld_ag(&pred[nbase + i]);
            }
        }

        // resets (all barrier-separated from their readers/writers):
        if (k >= 1 && tid < 32) st_ag(&coef[pp*(BATCHES*FDIM) + bid*32 + tid], 0.0);
        if (k < STEPS && bid == 0 && tid < 16) stu64_ag(&minr[p*16 + tid], DINF);

        __syncthreads();   // s_xp (and s_d) complete

        // lin += q . x_k
        double lp = (tid < ROWS_PER_BLK) ? (double)q[row_base + tid] * xv : 0.0;
        double ls = block_reduce_sum(lp, s_red);
        if (tid == 0) unsafeAtomicAdd(&lin[p*16 + batch], ls);

        // quad += w * x_k[s] * x_k[d]  (edge stream from global as verified;
        // x endpoints from LDS instead of random agent-scope LLC gathers)
        {
            const int e0 = bid * EDGE_PER_BLK;
            double qp = 0.0;
            #pragma unroll 4
            for (int j = 0; j < EDGE_PER_BLK/NTHR; ++j) {
                int e  = e0 + tid + j*NTHR;
                int si = edge_index[e];
                int di = edge_index[ETOT + e];
                qp += (double)edge_weight[e] * s_xp[si - nbase] * s_xp[di - nbase];
            }
            double qs = block_reduce_sum(qp, s_red);
            if (tid == 0) unsafeAtomicAdd(&quad[p*16 + batch], qs);
        }

        // coef += P^T d   (block-own rows only — no sync needed beyond LDS)
        if (k < STEPS) {
            double a0 = 0.0, a1 = 0.0, a2 = 0.0, a3 = 0.0;
            const float4* P4 = (const float4*)(proj + (size_t)row_base * FDIM);
            #pragma unroll 8
            for (int r = 0; r < ROWS_PER_BLK; ++r) {
                float4 pv = P4[r*(FDIM/4) + tid];
                double dv = s_d[r];
                a0 += (double)pv.x*dv; a1 += (double)pv.y*dv;
                a2 += (double)pv.z*dv; a3 += (double)pv.w*dv;
            }
            double* cf = coef + p*(BATCHES*FDIM) + batch*FDIM + 4*tid;
            unsafeAtomicAdd(cf+0, a0); unsafeAtomicAdd(cf+1, a1);
            unsafeAtomicAdd(cf+2, a2); unsafeAtomicAdd(cf+3, a3);
        }
        grid_barrier(bar, ++g, tid);

        // ================= Phase B =================
        double cur = 0.5 * ld_ag(&quad[p*16 + batch]) + ld_ag(&lin[p*16 + batch]);
        double bo  = s_bestobj;
        bool better = cur < bo;
        double nb  = better ? cur : bo;
        __syncthreads();
        if (tid == 0) s_bestobj = nb;

        if ((bid % BLK_PER_BATCH) == 0 && tid == 0) {
            double opt = (double)obj_solution[batch];
            double gap = fabs((opt - nb)/opt);
            if (k >= 1)     out[NTOT + BATCHES + batch*STEPS + (k-1)] = (float)gap;
            if (k == STEPS) out[NTOT + batch] = (float)gap;
        }
        if (better && tid < ROWS_PER_BLK)
            out[row_base + tid] = (float)s_x[tid];

        if (k == STEPS) break;

        if (bid == 0 && tid < 16) {     // zero next step's obj accumulators
            st_ag(&quad[pp*16 + tid], 0.0);
            st_ag(&lin[pp*16 + tid],  0.0);
        }

        // stage coef -> LDS
        #pragma unroll
        for (int j = 0; j < 4; ++j)
            s_coef[tid + 256*j] = ld_ag(&coef[p*(BATCHES*FDIM) + batch*FDIM + tid + 256*j]);
        __syncthreads();

        // pred = P coef  (own rows), ratio min
        {
            const int wave = tid >> 6, lane = tid & 63;
            double c[16];
            #pragma unroll
            for (int j = 0; j < 4; ++j) {
                int f = 4*(lane + 64*j);
                c[4*j+0] = s_coef[f+0]; c[4*j+1] = s_coef[f+1];
                c[4*j+2] = s_coef[f+2]; c[4*j+3] = s_coef[f+3];
            }
            double wmin = 1e300;
            for (int i = 0; i < ROWS_PER_BLK/4; ++i) {
                int r  = wave * (ROWS_PER_BLK/4) + i;
                int gr = row_base + r;
                const float4* Pr = (const float4*)(proj + (size_t)gr * FDIM);
                double dot = 0.0;
                #pragma unroll
                for (int j = 0; j < 4; ++j) {
                    float4 pv = Pr[lane + 64*j];
                    dot += (double)pv.x*c[4*j+0] + (double)pv.y*c[4*j+1]
                         + (double)pv.z*c[4*j+2] + (double)pv.w*c[4*j+3];
                }
                for (int off = 32; off > 0; off >>= 1)
                    dot += __shfl_down(dot, off, 64);
                if (lane == 0) {
                    s_pred[r] = dot;
                    st_ag(&pred[gr], dot);
                    if (dot < 0.0) wmin = fmin(wmin, s_x[r] / (-dot));
                }
            }
            if (lane == 0)
                atomicMin(&minr[p*16 + batch], (unsigned long long)__double_as_longlong(wmin));
        }
        grid_barrier(bar, ++g, tid);
    }
}

extern "C" void kernel_launch(void* const* d_in, const int* in_sizes, int n_in,
                              void* d_out, int out_size, void* d_ws, size_t ws_size,
                              hipStream_t stream) {
    const float* x_start      = (const float*)d_in[0];
    const float* rhs          = (const float*)d_in[1];
    const float* proj         = (const float*)d_in[2];
    const float* q            = (const float*)d_in[3];
    const float* obj_solution = (const float*)d_in[4];
    const int*   edge_index   = (const int*)d_in[5];
    const float* edge_weight  = (const float*)d_in[6];
    float* out = (float*)d_out;
    void* ws   = d_ws;

    // zero the barrier cells (arrive, gen) — ws is poisoned 0xAA each launch
    hipMemsetAsync((char*)d_ws + (size_t)WS_BAR * 8, 0, 16, stream);

    // PLAIN launch (not cooperative): the grid barrier is hand-rolled
    // atomics, so only physical co-residency matters (2 blocks/CU x 26.6KB
    // = 53KB <= 160KB LDS; 8 waves/CU <= 32). The cooperative launcher's
    // occupancy pre-check was rejecting LDS-heavy variants (rounds 2-4,6:
    // deterministic "outputs never written" signature).
    hipLaunchKernelGGL(GradSolver_58102317580919_kernel,
                       dim3(NBLK), dim3(NTHR), 0, stream,
                       x_start, rhs, proj, q, obj_solution,
                       edge_index, edge_weight, out, ws);
}